// Round 5
// baseline (336.415 us; speedup 1.0000x reference)
//
#include <hip/hip_runtime.h>
#include <hip/hip_bf16.h>

typedef __bf16 bf16x8 __attribute__((ext_vector_type(8)));
typedef float f32x4 __attribute__((ext_vector_type(4)));

static __device__ __forceinline__ unsigned short f32_to_bf16(float f) {
    union { float f; unsigned u; } v; v.f = f;
    unsigned u = v.u;
    u += 0x7FFFu + ((u >> 16) & 1u);   // RNE
    return (unsigned short)(u >> 16);
}

// async global->LDS, 16 B per lane. LDS dest = wave-uniform base + lane*16.
static __device__ __forceinline__ void async_load16(const unsigned short* g,
                                                    unsigned short* l) {
    __builtin_amdgcn_global_load_lds(
        (__attribute__((address_space(1))) const unsigned int*)(const void*)g,
        (__attribute__((address_space(3))) unsigned int*)(void*)l,
        16, 0, 0);
}

// ---------------- cast f32 -> bf16, vectorized ----------------
__global__ void cast_f32_bf16(const float* __restrict__ src,
                              unsigned short* __restrict__ dst, int n4) {
    int i = blockIdx.x * blockDim.x + threadIdx.x;
    if (i < n4) {
        float4 f = ((const float4*)src)[i];
        ushort4 o;
        o.x = f32_to_bf16(f.x); o.y = f32_to_bf16(f.y);
        o.z = f32_to_bf16(f.z); o.w = f32_to_bf16(f.w);
        ((ushort4*)dst)[i] = o;
    }
}

// ---------------- transpose + cast: src f32 [R][C] -> dst bf16 [C][R] ----------------
__global__ void transpose_cast(const float* __restrict__ src,
                               unsigned short* __restrict__ dst, int R, int C) {
    __shared__ float tile[32][33];
    int c0 = blockIdx.x * 32, r0 = blockIdx.y * 32;
    int tx = threadIdx.x, ty = threadIdx.y;   // 32 x 8
    #pragma unroll
    for (int i = 0; i < 32; i += 8)
        tile[ty + i][tx] = src[(long)(r0 + ty + i) * C + c0 + tx];
    __syncthreads();
    #pragma unroll
    for (int i = 0; i < 32; i += 8)
        dst[(long)(c0 + ty + i) * R + r0 + tx] = f32_to_bf16(tile[tx][ty + i]);
}

// ---------------- bf16 MFMA GEMM, m97-style async staging ----------------
// C[M][N] = (A[M][K] * Bt[N][K]^T + bias) * (col < scale_ncols ? scale : 1)
template<bool OUT_BF16>
__global__ __launch_bounds__(256) void gemm_bt_bias(
    const unsigned short* __restrict__ A,    // [M][K] bf16
    const unsigned short* __restrict__ Bt,   // [N][K] bf16
    const float* __restrict__ bias,          // [N] f32
    void* __restrict__ Cout,                 // [M][N] bf16 or f32
    int M, int N, int K, int scale_ncols, float scale)
{
    __shared__ __align__(16) unsigned short As[128 * 32];
    __shared__ __align__(16) unsigned short Bs[128 * 32];

    const int tid  = threadIdx.x;
    const int m0   = blockIdx.x * 128;
    const int n0   = blockIdx.y * 128;
    const int w    = tid >> 6, lane = tid & 63;
    const int quad = lane >> 4, lr = lane & 15;
    const int wm   = (w >> 1) * 64, wn = (w & 1) * 64;

    f32x4 acc[4][4];
    #pragma unroll
    for (int i = 0; i < 4; i++)
        #pragma unroll
        for (int j = 0; j < 4; j++)
            acc[i][j] = (f32x4){0.f, 0.f, 0.f, 0.f};

    const int srow = lane >> 2;
    const int soff = (lane & 3) * 8;
    const unsigned short* gA0 = &A [(long)(m0 + w * 16 + srow) * K + soff];
    const unsigned short* gA1 = &A [(long)(m0 + 64 + w * 16 + srow) * K + soff];
    const unsigned short* gB0 = &Bt[(long)(n0 + w * 16 + srow) * K + soff];
    const unsigned short* gB1 = &Bt[(long)(n0 + 64 + w * 16 + srow) * K + soff];
    unsigned short* lA0 = &As[(w * 16) * 32];
    unsigned short* lA1 = &As[(64 + w * 16) * 32];
    unsigned short* lB0 = &Bs[(w * 16) * 32];
    unsigned short* lB1 = &Bs[(64 + w * 16) * 32];

    for (int k0 = 0; k0 < K; k0 += 32) {
        __syncthreads();
        async_load16(gA0 + k0, lA0);
        async_load16(gA1 + k0, lA1);
        async_load16(gB0 + k0, lB0);
        async_load16(gB1 + k0, lB1);
        __syncthreads();   // barrier drain waits vmcnt(0)

        bf16x8 af[4], bfr[4];
        #pragma unroll
        for (int i = 0; i < 4; i++)
            af[i] = *(const bf16x8*)&As[(wm + i * 16 + lr) * 32 + quad * 8];
        #pragma unroll
        for (int j = 0; j < 4; j++)
            bfr[j] = *(const bf16x8*)&Bs[(wn + j * 16 + lr) * 32 + quad * 8];
        #pragma unroll
        for (int i = 0; i < 4; i++)
            #pragma unroll
            for (int j = 0; j < 4; j++)
                acc[i][j] = __builtin_amdgcn_mfma_f32_16x16x32_bf16(af[i], bfr[j], acc[i][j], 0, 0, 0);
    }

    #pragma unroll
    for (int i = 0; i < 4; i++) {
        #pragma unroll
        for (int j = 0; j < 4; j++) {
            int gcol = n0 + wn + j * 16 + lr;
            float bv = bias[gcol];
            float sc = (gcol < scale_ncols) ? scale : 1.0f;
            #pragma unroll
            for (int r = 0; r < 4; r++) {
                int grow = m0 + wm + i * 16 + quad * 4 + r;
                float v = (acc[i][j][r] + bv) * sc;
                if (OUT_BF16)
                    ((unsigned short*)Cout)[(long)grow * N + gcol] = f32_to_bf16(v);
                else
                    ((float*)Cout)[(long)grow * N + gcol] = v;
            }
        }
    }
}

// ---------------- V transpose: qkv V-section [b,t][h,d] -> vT [b,h,d][t] ----------------
__global__ __launch_bounds__(256) void transpose_v(
    const unsigned short* __restrict__ qkv,  // [B*T][3C] bf16
    unsigned short* __restrict__ vT,         // [B*H*64][T] bf16
    int T, int C3, int C, int H)
{
    __shared__ __align__(16) unsigned short tile[64 * 72];  // [t][d]
    const int tid = threadIdx.x;
    const int t0 = blockIdx.x * 64, h = blockIdx.y, b = blockIdx.z;
    const long ibase = ((long)b * T + t0) * C3 + 2 * C + h * 64;
    #pragma unroll
    for (int c = tid; c < 512; c += 256) {
        int r = c >> 3, off = (c & 7) * 8;
        *(uint4*)&tile[r * 72 + off] = *(const uint4*)&qkv[ibase + (long)r * C3 + off];
    }
    __syncthreads();
    const long obase = (long)((b * H + h) * 64) * T + t0;
    #pragma unroll
    for (int c = tid; c < 512; c += 256) {
        int d = c & 63, tc = c >> 6;
        unsigned short tmp[8];
        #pragma unroll
        for (int j = 0; j < 8; j++)
            tmp[j] = tile[(tc * 8 + j) * 72 + d];
        *(uint4*)&vT[obase + (long)d * T + tc * 8] = *(const uint4*)tmp;
    }
}

// ---------------- MFMA causal flash attention, Q-tile 128, Q in registers ----------------
// grid (NT/2, H, B). Block handles q-tiles x and NT-1-x -> uniform 34 K-iters.
// 4 waves; wave w owns 32 q-rows held as register fragments (loaded once per
// tile). Softmax: fixed reference m=0; scale pre-folded into q at the QKV GEMM.
// LDS = Ks+Vs+Ps = 36.9 KB -> 4 blocks/CU.
__global__ __launch_bounds__(256, 4) void attn_mfma(
    const unsigned short* __restrict__ qkv,  // [B*T][3C] bf16 (q pre-scaled)
    const unsigned short* __restrict__ vT,   // [B*H*64][T] bf16
    unsigned short* __restrict__ yb,         // [B*T][C]  bf16
    int T, int C3, int C, int H, int NT)
{
    constexpr int SQ = 72;
    __shared__ __align__(16) unsigned short Ks[64 * SQ];
    __shared__ __align__(16) unsigned short Vs[64 * SQ];   // [d][key]
    __shared__ __align__(16) unsigned short Ps[128 * SQ];

    const int tid = threadIdx.x;
    const int h   = blockIdx.y;
    const int b   = blockIdx.z;
    const long rowbase = (long)b * T;
    const long vtbase  = (long)((b * H + h) * 64) * T;

    const int w = tid >> 6, lane = tid & 63;
    const int quad = lane >> 4, lr = lane & 15;

    const int r0 = tid >> 3, off0 = (tid & 7) * 8;   // staging: rows 0..31, 16B chunks
    const int r1 = r0 + 32;

    for (int t = 0; t < 2; t++) {
        const int qt = (t == 0) ? blockIdx.x : (NT - 1 - blockIdx.x);
        const int q0 = qt * 128;
        const int nb = 2 * qt + 2;

        const int wrow0 = w * 32;            // wave's first row within tile
        const int wrowmax = q0 + wrow0 + 31; // wave's last global row

        // Q fragments in registers: [st][ks], st = 16-row subtile, ks = 32-k half
        bf16x8 aq[2][2];
        #pragma unroll
        for (int st = 0; st < 2; st++)
            #pragma unroll
            for (int ks = 0; ks < 2; ks++)
                aq[st][ks] = *(const bf16x8*)&qkv[
                    (rowbase + q0 + wrow0 + st * 16 + lr) * (long)C3 + h * 64 + ks * 32 + quad * 8];

        // prefetch kb=0 K/V into registers
        uint4 pk0, pk1, pv0, pv1;
        {
            long g0 = (rowbase + r0) * (long)C3 + C + h * 64 + off0;
            long g1 = (rowbase + r1) * (long)C3 + C + h * 64 + off0;
            pk0 = *(const uint4*)&qkv[g0];
            pk1 = *(const uint4*)&qkv[g1];
            pv0 = *(const uint4*)&vT[vtbase + (long)r0 * T + off0];
            pv1 = *(const uint4*)&vT[vtbase + (long)r1 * T + off0];
        }

        f32x4 oA[2][4];
        float lp[8];
        #pragma unroll
        for (int st = 0; st < 2; st++)
            #pragma unroll
            for (int j = 0; j < 4; j++) oA[st][j] = (f32x4){0.f, 0.f, 0.f, 0.f};
        #pragma unroll
        for (int i = 0; i < 8; i++) lp[i] = 0.f;

        for (int kb = 0; kb < nb; kb++) {
            __syncthreads();   // prior-iteration Ks/Vs reads done
            *(uint4*)&Ks[r0 * SQ + off0] = pk0;
            *(uint4*)&Ks[r1 * SQ + off0] = pk1;
            *(uint4*)&Vs[r0 * SQ + off0] = pv0;
            *(uint4*)&Vs[r1 * SQ + off0] = pv1;
            __syncthreads();

            // prefetch kb+1 (latency overlaps compute below)
            if (kb + 1 < nb) {
                long g0 = (rowbase + (kb + 1) * 64 + r0) * (long)C3 + C + h * 64 + off0;
                long g1 = (rowbase + (kb + 1) * 64 + r1) * (long)C3 + C + h * 64 + off0;
                pk0 = *(const uint4*)&qkv[g0];
                pk1 = *(const uint4*)&qkv[g1];
                pv0 = *(const uint4*)&vT[vtbase + (long)r0 * T + (kb + 1) * 64 + off0];
                pv1 = *(const uint4*)&vT[vtbase + (long)r1 * T + (kb + 1) * 64 + off0];
            }

            // wave-uniform skip: all 32 rows fully masked (only on final diagonal block)
            if (kb * 64 > wrowmax) continue;   // no barriers inside the guarded region

            // ---- S = Q K^T : 32 x 64 per wave (2 subtiles) ----
            f32x4 sA[2][4];
            #pragma unroll
            for (int st = 0; st < 2; st++)
                #pragma unroll
                for (int j = 0; j < 4; j++) sA[st][j] = (f32x4){0.f, 0.f, 0.f, 0.f};
            #pragma unroll
            for (int ks = 0; ks < 2; ks++) {
                #pragma unroll
                for (int jt = 0; jt < 4; jt++) {
                    bf16x8 bk = *(const bf16x8*)&Ks[(jt * 16 + lr) * SQ + ks * 32 + quad * 8];
                    sA[0][jt] = __builtin_amdgcn_mfma_f32_16x16x32_bf16(aq[0][ks], bk, sA[0][jt], 0, 0, 0);
                    sA[1][jt] = __builtin_amdgcn_mfma_f32_16x16x32_bf16(aq[1][ks], bk, sA[1][jt], 0, 0, 0);
                }
            }

            // ---- softmax, fixed reference m=0 (scale pre-folded into q) ----
            const bool diag = (kb >= nb - 2);
            #pragma unroll
            for (int st = 0; st < 2; st++) {
                #pragma unroll
                for (int r = 0; r < 4; r++) {
                    int rowin = q0 + wrow0 + st * 16 + quad * 4 + r;
                    #pragma unroll
                    for (int jt = 0; jt < 4; jt++) {
                        float sv = sA[st][jt][r];
                        if (diag && (kb * 64 + jt * 16 + lr) > rowin) sv = -1e30f;
                        float p = exp2f(sv);
                        lp[st * 4 + r] += p;
                        Ps[(wrow0 + st * 16 + quad * 4 + r) * SQ + jt * 16 + lr] = f32_to_bf16(p);
                    }
                }
            }
            // same-wave Ps write->read: program order + compiler lgkmcnt

            // ---- O += P V ----
            #pragma unroll
            for (int ks = 0; ks < 2; ks++) {
                bf16x8 ap0 = *(const bf16x8*)&Ps[(wrow0 + lr) * SQ + ks * 32 + quad * 8];
                bf16x8 ap1 = *(const bf16x8*)&Ps[(wrow0 + 16 + lr) * SQ + ks * 32 + quad * 8];
                #pragma unroll
                for (int jt = 0; jt < 4; jt++) {
                    bf16x8 bv = *(const bf16x8*)&Vs[(jt * 16 + lr) * SQ + ks * 32 + quad * 8];
                    oA[0][jt] = __builtin_amdgcn_mfma_f32_16x16x32_bf16(ap0, bv, oA[0][jt], 0, 0, 0);
                    oA[1][jt] = __builtin_amdgcn_mfma_f32_16x16x32_bf16(ap1, bv, oA[1][jt], 0, 0, 0);
                }
            }
        }

        // ---- reduce row-sums once, normalize + store ----
        #pragma unroll
        for (int st = 0; st < 2; st++) {
            #pragma unroll
            for (int r = 0; r < 4; r++) {
                float l = lp[st * 4 + r];
                l += __shfl_xor(l, 1);
                l += __shfl_xor(l, 2);
                l += __shfl_xor(l, 4);
                l += __shfl_xor(l, 8);
                float inv = 1.f / l;
                long grow = rowbase + q0 + wrow0 + st * 16 + quad * 4 + r;
                #pragma unroll
                for (int jt = 0; jt < 4; jt++)
                    yb[grow * C + h * 64 + jt * 16 + lr] = f32_to_bf16(oA[st][jt][r] * inv);
            }
        }
    }
}

extern "C" void kernel_launch(void* const* d_in, const int* in_sizes, int n_in,
                              void* d_out, int out_size, void* d_ws, size_t ws_size,
                              hipStream_t stream) {
    const float* x      = (const float*)d_in[0];
    const float* W_attn = (const float*)d_in[1];
    const float* b_attn = (const float*)d_in[2];
    const float* W_proj = (const float*)d_in[3];
    const float* b_proj = (const float*)d_in[4];
    float* out = (float*)d_out;

    const int B = 4, T = 2048, C = 1024, H = 16;
    const int M  = B * T;     // 8192
    const int C3 = 3 * C;     // 3072
    const int NT = T / 128;   // 16
    // log2(e)/sqrt(64): folds softmax base-2 conversion and 1/sqrt(hd) into q
    const float scale2 = 0.18033688011112042f;

    char* ws = (char*)d_ws;
    size_t off = 0;
    auto carve = [&](size_t bytes) {
        char* p = ws + off;
        off += (bytes + 255) & ~(size_t)255;
        return p;
    };
    unsigned short* xb   = (unsigned short*)carve((size_t)M * C * 2);    // x bf16; reused as vT
    unsigned short* wat  = (unsigned short*)carve((size_t)C3 * C * 2);
    unsigned short* wpt  = (unsigned short*)carve((size_t)C * C * 2);
    unsigned short* qkvb = (unsigned short*)carve((size_t)M * C3 * 2);
    unsigned short* ybuf = (unsigned short*)carve((size_t)M * C * 2);
    unsigned short* vTb  = xb;   // alias: xb dead after QKV GEMM

    cast_f32_bf16<<<(M * C / 4 + 255) / 256, 256, 0, stream>>>(x, xb, M * C / 4);
    transpose_cast<<<dim3(C3 / 32, C / 32), dim3(32, 8), 0, stream>>>(W_attn, wat, C, C3);
    transpose_cast<<<dim3(C / 32, C / 32), dim3(32, 8), 0, stream>>>(W_proj, wpt, C, C);

    gemm_bt_bias<true><<<dim3(M / 128, C3 / 128), 256, 0, stream>>>(
        xb, wat, b_attn, qkvb, M, C3, C, C, scale2);

    transpose_v<<<dim3(T / 64, H, B), 256, 0, stream>>>(qkvb, vTb, T, C3, C, H);

    attn_mfma<<<dim3(NT / 2, H, B), 256, 0, stream>>>(qkvb, vTb, ybuf, T, C3, C, H, NT);

    gemm_bt_bias<false><<<dim3(M / 128, C / 128), 256, 0, stream>>>(
        ybuf, wpt, b_proj, out, M, C, C, 0, 1.0f);
}

// Round 7
// 291.430 us; speedup vs baseline: 1.1544x; 1.1544x over previous
//
#include <hip/hip_runtime.h>
#include <hip/hip_bf16.h>

typedef __bf16 bf16x8 __attribute__((ext_vector_type(8)));
typedef float f32x4 __attribute__((ext_vector_type(4)));

static __device__ __forceinline__ unsigned short f32_to_bf16(float f) {
    union { float f; unsigned u; } v; v.f = f;
    unsigned u = v.u;
    u += 0x7FFFu + ((u >> 16) & 1u);   // RNE
    return (unsigned short)(u >> 16);
}
static __device__ __forceinline__ unsigned pack_bf16x2(float a, float b) {
    return ((unsigned)f32_to_bf16(a)) | (((unsigned)f32_to_bf16(b)) << 16);
}

// async global->LDS, 16 B per lane. LDS dest = wave-uniform base + lane*16.
static __device__ __forceinline__ void async_load16(const unsigned short* g,
                                                    unsigned short* l) {
    __builtin_amdgcn_global_load_lds(
        (__attribute__((address_space(1))) const unsigned int*)(const void*)g,
        (__attribute__((address_space(3))) unsigned int*)(void*)l,
        16, 0, 0);
}

// ---------------- cast f32 -> bf16, vectorized ----------------
__global__ void cast_f32_bf16(const float* __restrict__ src,
                              unsigned short* __restrict__ dst, int n4) {
    int i = blockIdx.x * blockDim.x + threadIdx.x;
    if (i < n4) {
        float4 f = ((const float4*)src)[i];
        ushort4 o;
        o.x = f32_to_bf16(f.x); o.y = f32_to_bf16(f.y);
        o.z = f32_to_bf16(f.z); o.w = f32_to_bf16(f.w);
        ((ushort4*)dst)[i] = o;
    }
}

// ---------------- transpose + cast: src f32 [R][C] -> dst bf16 [C][R] ----------------
__global__ void transpose_cast(const float* __restrict__ src,
                               unsigned short* __restrict__ dst, int R, int C) {
    __shared__ float tile[32][33];
    int c0 = blockIdx.x * 32, r0 = blockIdx.y * 32;
    int tx = threadIdx.x, ty = threadIdx.y;   // 32 x 8
    #pragma unroll
    for (int i = 0; i < 32; i += 8)
        tile[ty + i][tx] = src[(long)(r0 + ty + i) * C + c0 + tx];
    __syncthreads();
    #pragma unroll
    for (int i = 0; i < 32; i += 8)
        dst[(long)(c0 + ty + i) * R + r0 + tx] = f32_to_bf16(tile[tx][ty + i]);
}

// ---------------- bf16 MFMA GEMM, m97 structure: BK=64, async width-16 staging ----------------
// C[M][N] = (A[M][K] * Bt[N][K]^T + bias) * (col < scale_ncols ? scale : 1)
template<bool OUT_BF16>
__global__ __launch_bounds__(256) void gemm_bt_bias(
    const unsigned short* __restrict__ A,    // [M][K] bf16
    const unsigned short* __restrict__ Bt,   // [N][K] bf16
    const float* __restrict__ bias,          // [N] f32
    void* __restrict__ Cout,                 // [M][N] bf16 or f32
    int M, int N, int K, int scale_ncols, float scale)
{
    __shared__ __align__(16) unsigned short As[128 * 64];
    __shared__ __align__(16) unsigned short Bs[128 * 64];

    const int tid  = threadIdx.x;
    const int m0   = blockIdx.x * 128;
    const int n0   = blockIdx.y * 128;
    const int w    = tid >> 6, lane = tid & 63;
    const int quad = lane >> 4, lr = lane & 15;
    const int wm   = (w >> 1) * 64, wn = (w & 1) * 64;

    f32x4 acc[4][4];
    #pragma unroll
    for (int i = 0; i < 4; i++)
        #pragma unroll
        for (int j = 0; j < 4; j++)
            acc[i][j] = (f32x4){0.f, 0.f, 0.f, 0.f};

    // staging: call c covers rows c*32 + w*8 + (lane>>3), k-chunk (lane&7)*8
    const int srow8 = lane >> 3;
    const int skoff = (lane & 7) * 8;

    for (int k0 = 0; k0 < K; k0 += 64) {
        __syncthreads();
        #pragma unroll
        for (int c = 0; c < 4; c++) {
            const int rbase = c * 32 + w * 8;
            async_load16(&A [(long)(m0 + rbase + srow8) * K + k0 + skoff], &As[rbase * 64]);
            async_load16(&Bt[(long)(n0 + rbase + srow8) * K + k0 + skoff], &Bs[rbase * 64]);
        }
        __syncthreads();   // barrier drain waits vmcnt(0)

        #pragma unroll
        for (int ks = 0; ks < 2; ks++) {
            bf16x8 af[4], bfr[4];
            #pragma unroll
            for (int i = 0; i < 4; i++)
                af[i] = *(const bf16x8*)&As[(wm + i * 16 + lr) * 64 + ks * 32 + quad * 8];
            #pragma unroll
            for (int j = 0; j < 4; j++)
                bfr[j] = *(const bf16x8*)&Bs[(wn + j * 16 + lr) * 64 + ks * 32 + quad * 8];
            #pragma unroll
            for (int i = 0; i < 4; i++)
                #pragma unroll
                for (int j = 0; j < 4; j++)
                    acc[i][j] = __builtin_amdgcn_mfma_f32_16x16x32_bf16(af[i], bfr[j], acc[i][j], 0, 0, 0);
        }
    }

    #pragma unroll
    for (int i = 0; i < 4; i++) {
        #pragma unroll
        for (int j = 0; j < 4; j++) {
            int gcol = n0 + wn + j * 16 + lr;
            float bv = bias[gcol];
            float sc = (gcol < scale_ncols) ? scale : 1.0f;
            #pragma unroll
            for (int r = 0; r < 4; r++) {
                int grow = m0 + wm + i * 16 + quad * 4 + r;
                float v = (acc[i][j][r] + bv) * sc;
                if (OUT_BF16)
                    ((unsigned short*)Cout)[(long)grow * N + gcol] = f32_to_bf16(v);
                else
                    ((float*)Cout)[(long)grow * N + gcol] = v;
            }
        }
    }
}

// ---------------- V transpose: qkv V-section [b,t][h,d] -> vT [b,h,d][t] ----------------
__global__ __launch_bounds__(256) void transpose_v(
    const unsigned short* __restrict__ qkv,  // [B*T][3C] bf16
    unsigned short* __restrict__ vT,         // [B*H*64][T] bf16
    int T, int C3, int C, int H)
{
    __shared__ __align__(16) unsigned short tile[64 * 72];  // [t][d]
    const int tid = threadIdx.x;
    const int t0 = blockIdx.x * 64, h = blockIdx.y, b = blockIdx.z;
    const long ibase = ((long)b * T + t0) * C3 + 2 * C + h * 64;
    #pragma unroll
    for (int c = tid; c < 512; c += 256) {
        int r = c >> 3, off = (c & 7) * 8;
        *(uint4*)&tile[r * 72 + off] = *(const uint4*)&qkv[ibase + (long)r * C3 + off];
    }
    __syncthreads();
    const long obase = (long)((b * H + h) * 64) * T + t0;
    #pragma unroll
    for (int c = tid; c < 512; c += 256) {
        int d = c & 63, tc = c >> 6;
        unsigned short tmp[8];
        #pragma unroll
        for (int j = 0; j < 8; j++)
            tmp[j] = tile[(tc * 8 + j) * 72 + d];
        *(uint4*)&vT[obase + (long)d * T + tc * 8] = *(const uint4*)tmp;
    }
}

// ---------------- MFMA causal flash attention ----------------
// Q-tile 128, Q in registers, TRANSPOSED-S: S^T = mfma(K_frag, Q_frag) puts
// q across lanes and keys in regs -> P written to LDS [q][key] row-major as
// ds_write_b64 (8/iter vs 32 scattered b16), PV reads stay b128. Softmax uses
// fixed reference m=0 (scale pre-folded into q at QKV GEMM) and raw v_exp_f32.
// LDS = Ks+Vs+Ps = 36.9 KB; launch_bounds(256,3) avoids round-5's spills.
__global__ __launch_bounds__(256, 3) void attn_mfma(
    const unsigned short* __restrict__ qkv,  // [B*T][3C] bf16 (q pre-scaled)
    const unsigned short* __restrict__ vT,   // [B*H*64][T] bf16
    unsigned short* __restrict__ yb,         // [B*T][C]  bf16
    int T, int C3, int C, int H, int NT)
{
    constexpr int SQ = 72;
    __shared__ __align__(16) unsigned short Ks[64 * SQ];
    __shared__ __align__(16) unsigned short Vs[64 * SQ];    // [d][key]
    __shared__ __align__(16) unsigned short Ps[128 * SQ];   // [q][key]

    const int tid = threadIdx.x;
    const int h   = blockIdx.y;
    const int b   = blockIdx.z;
    const long rowbase = (long)b * T;
    const long vtbase  = (long)((b * H + h) * 64) * T;

    const int w = tid >> 6, lane = tid & 63;
    const int quad = lane >> 4, lr = lane & 15;

    const int r0 = tid >> 3, off0 = (tid & 7) * 8;   // staging: rows 0..31, 16B chunks
    const int r1 = r0 + 32;

    for (int t = 0; t < 2; t++) {
        const int qt = (t == 0) ? blockIdx.x : (NT - 1 - blockIdx.x);
        const int q0 = qt * 128;
        const int nb = 2 * qt + 2;

        const int wrow0 = w * 32;            // wave's first row within tile
        const int wrowmax = q0 + wrow0 + 31; // wave's last global row

        // Q fragments in registers: [st][ks]; B-operand layout = rows of Q, d-contiguous
        bf16x8 aq[2][2];
        #pragma unroll
        for (int st = 0; st < 2; st++)
            #pragma unroll
            for (int ks = 0; ks < 2; ks++)
                aq[st][ks] = *(const bf16x8*)&qkv[
                    (rowbase + q0 + wrow0 + st * 16 + lr) * (long)C3 + h * 64 + ks * 32 + quad * 8];

        // prefetch kb=0 K/V into registers
        uint4 pk0, pk1, pv0, pv1;
        {
            long g0 = (rowbase + r0) * (long)C3 + C + h * 64 + off0;
            long g1 = (rowbase + r1) * (long)C3 + C + h * 64 + off0;
            pk0 = *(const uint4*)&qkv[g0];
            pk1 = *(const uint4*)&qkv[g1];
            pv0 = *(const uint4*)&vT[vtbase + (long)r0 * T + off0];
            pv1 = *(const uint4*)&vT[vtbase + (long)r1 * T + off0];
        }

        f32x4 oA[2][4];
        float lp[2] = {0.f, 0.f};
        #pragma unroll
        for (int st = 0; st < 2; st++)
            #pragma unroll
            for (int j = 0; j < 4; j++) oA[st][j] = (f32x4){0.f, 0.f, 0.f, 0.f};

        for (int kb = 0; kb < nb; kb++) {
            __syncthreads();   // prior-iteration Ks/Vs reads done
            *(uint4*)&Ks[r0 * SQ + off0] = pk0;
            *(uint4*)&Ks[r1 * SQ + off0] = pk1;
            *(uint4*)&Vs[r0 * SQ + off0] = pv0;
            *(uint4*)&Vs[r1 * SQ + off0] = pv1;
            __syncthreads();

            // prefetch kb+1 (latency overlaps compute below)
            if (kb + 1 < nb) {
                long g0 = (rowbase + (kb + 1) * 64 + r0) * (long)C3 + C + h * 64 + off0;
                long g1 = (rowbase + (kb + 1) * 64 + r1) * (long)C3 + C + h * 64 + off0;
                pk0 = *(const uint4*)&qkv[g0];
                pk1 = *(const uint4*)&qkv[g1];
                pv0 = *(const uint4*)&vT[vtbase + (long)r0 * T + (kb + 1) * 64 + off0];
                pv1 = *(const uint4*)&vT[vtbase + (long)r1 * T + (kb + 1) * 64 + off0];
            }

            // wave-uniform skip: all 32 rows fully masked
            if (kb * 64 > wrowmax) continue;   // no barriers inside guarded region

            // ---- S^T = K Q^T : D[m=key][n=q] per 16x16 tile ----
            f32x4 sT[2][4];
            #pragma unroll
            for (int st = 0; st < 2; st++)
                #pragma unroll
                for (int j = 0; j < 4; j++) sT[st][j] = (f32x4){0.f, 0.f, 0.f, 0.f};
            #pragma unroll
            for (int ks = 0; ks < 2; ks++) {
                #pragma unroll
                for (int jt = 0; jt < 4; jt++) {
                    bf16x8 kf = *(const bf16x8*)&Ks[(jt * 16 + lr) * SQ + ks * 32 + quad * 8];
                    sT[0][jt] = __builtin_amdgcn_mfma_f32_16x16x32_bf16(kf, aq[0][ks], sT[0][jt], 0, 0, 0);
                    sT[1][jt] = __builtin_amdgcn_mfma_f32_16x16x32_bf16(kf, aq[1][ks], sT[1][jt], 0, 0, 0);
                }
            }

            // ---- softmax (fixed ref m=0): lane owns q = st*16+lr, keys jt*16+quad*4+r ----
            // mask needed iff this block contains any key > the wave's SMALLEST q
            const bool diag = (kb * 64 + 63 > q0 + wrow0);   // wave-uniform, fixes r6 bug
            #pragma unroll
            for (int st = 0; st < 2; st++) {
                const int qg = q0 + wrow0 + st * 16 + lr;
                float rowsum = 0.f;
                #pragma unroll
                for (int jt = 0; jt < 4; jt++) {
                    float p[4];
                    #pragma unroll
                    for (int r = 0; r < 4; r++) {
                        float sv = sT[st][jt][r];
                        if (diag && (kb * 64 + jt * 16 + quad * 4 + r) > qg) sv = -1e30f;
                        p[r] = __builtin_amdgcn_exp2f(sv);
                        rowsum += p[r];
                    }
                    *(uint2*)&Ps[(wrow0 + st * 16 + lr) * SQ + jt * 16 + quad * 4] =
                        make_uint2(pack_bf16x2(p[0], p[1]), pack_bf16x2(p[2], p[3]));
                }
                lp[st] += rowsum;
            }
            // same-wave Ps write->read: program order + compiler lgkmcnt

            // ---- O += P V : ap = P rows (q, key-contig), bv = V^T rows (d, key-contig) ----
            #pragma unroll
            for (int ks = 0; ks < 2; ks++) {
                bf16x8 ap0 = *(const bf16x8*)&Ps[(wrow0 + lr) * SQ + ks * 32 + quad * 8];
                bf16x8 ap1 = *(const bf16x8*)&Ps[(wrow0 + 16 + lr) * SQ + ks * 32 + quad * 8];
                #pragma unroll
                for (int jt = 0; jt < 4; jt++) {
                    bf16x8 bv = *(const bf16x8*)&Vs[(jt * 16 + lr) * SQ + ks * 32 + quad * 8];
                    oA[0][jt] = __builtin_amdgcn_mfma_f32_16x16x32_bf16(ap0, bv, oA[0][jt], 0, 0, 0);
                    oA[1][jt] = __builtin_amdgcn_mfma_f32_16x16x32_bf16(ap1, bv, oA[1][jt], 0, 0, 0);
                }
            }
        }

        // ---- reduce row-sums across quads, redistribute, normalize + store ----
        #pragma unroll
        for (int st = 0; st < 2; st++) {
            float l = lp[st];
            l += __shfl_xor(l, 16);
            l += __shfl_xor(l, 32);
            float inv = 1.f / l;   // valid for q = st*16+lr (all quads hold it)
            #pragma unroll
            for (int r = 0; r < 4; r++) {
                float invr = __shfl(inv, quad * 4 + r, 16);  // inv for row quad*4+r
                long grow = rowbase + q0 + wrow0 + st * 16 + quad * 4 + r;
                #pragma unroll
                for (int jt = 0; jt < 4; jt++)
                    yb[grow * C + h * 64 + jt * 16 + lr] = f32_to_bf16(oA[st][jt][r] * invr);
            }
        }
    }
}

extern "C" void kernel_launch(void* const* d_in, const int* in_sizes, int n_in,
                              void* d_out, int out_size, void* d_ws, size_t ws_size,
                              hipStream_t stream) {
    const float* x      = (const float*)d_in[0];
    const float* W_attn = (const float*)d_in[1];
    const float* b_attn = (const float*)d_in[2];
    const float* W_proj = (const float*)d_in[3];
    const float* b_proj = (const float*)d_in[4];
    float* out = (float*)d_out;

    const int B = 4, T = 2048, C = 1024, H = 16;
    const int M  = B * T;     // 8192
    const int C3 = 3 * C;     // 3072
    const int NT = T / 128;   // 16
    // log2(e)/sqrt(64): folds softmax base-2 conversion and 1/sqrt(hd) into q
    const float scale2 = 0.18033688011112042f;

    char* ws = (char*)d_ws;
    size_t off = 0;
    auto carve = [&](size_t bytes) {
        char* p = ws + off;
        off += (bytes + 255) & ~(size_t)255;
        return p;
    };
    unsigned short* xb   = (unsigned short*)carve((size_t)M * C * 2);    // x bf16; reused as vT
    unsigned short* wat  = (unsigned short*)carve((size_t)C3 * C * 2);
    unsigned short* wpt  = (unsigned short*)carve((size_t)C * C * 2);
    unsigned short* qkvb = (unsigned short*)carve((size_t)M * C3 * 2);
    unsigned short* ybuf = (unsigned short*)carve((size_t)M * C * 2);
    unsigned short* vTb  = xb;   // alias: xb dead after QKV GEMM

    cast_f32_bf16<<<(M * C / 4 + 255) / 256, 256, 0, stream>>>(x, xb, M * C / 4);
    transpose_cast<<<dim3(C3 / 32, C / 32), dim3(32, 8), 0, stream>>>(W_attn, wat, C, C3);
    transpose_cast<<<dim3(C / 32, C / 32), dim3(32, 8), 0, stream>>>(W_proj, wpt, C, C);

    gemm_bt_bias<true><<<dim3(M / 128, C3 / 128), 256, 0, stream>>>(
        xb, wat, b_attn, qkvb, M, C3, C, C, scale2);

    transpose_v<<<dim3(T / 64, H, B), 256, 0, stream>>>(qkvb, vTb, T, C3, C, H);

    attn_mfma<<<dim3(NT / 2, H, B), 256, 0, stream>>>(qkvb, vTb, ybuf, T, C3, C, H, NT);

    gemm_bt_bias<false><<<dim3(M / 128, C / 128), 256, 0, stream>>>(
        ybuf, wpt, b_proj, out, M, C, C, 0, 1.0f);
}

// Round 8
// 258.689 us; speedup vs baseline: 1.3005x; 1.1266x over previous
//
#include <hip/hip_runtime.h>
#include <hip/hip_bf16.h>

typedef __bf16 bf16x8 __attribute__((ext_vector_type(8)));
typedef float f32x4 __attribute__((ext_vector_type(4)));

static __device__ __forceinline__ unsigned short f32_to_bf16(float f) {
    union { float f; unsigned u; } v; v.f = f;
    unsigned u = v.u;
    u += 0x7FFFu + ((u >> 16) & 1u);   // RNE
    return (unsigned short)(u >> 16);
}
static __device__ __forceinline__ unsigned pack_bf16x2(float a, float b) {
    return ((unsigned)f32_to_bf16(a)) | (((unsigned)f32_to_bf16(b)) << 16);
}

// async global->LDS, 16 B per lane. LDS dest = wave-uniform base + lane*16.
static __device__ __forceinline__ void async_load16(const unsigned short* g,
                                                    unsigned short* l) {
    __builtin_amdgcn_global_load_lds(
        (__attribute__((address_space(1))) const unsigned int*)(const void*)g,
        (__attribute__((address_space(3))) unsigned int*)(void*)l,
        16, 0, 0);
}

// ---------------- cast f32 -> bf16, vectorized ----------------
__global__ void cast_f32_bf16(const float* __restrict__ src,
                              unsigned short* __restrict__ dst, int n4) {
    int i = blockIdx.x * blockDim.x + threadIdx.x;
    if (i < n4) {
        float4 f = ((const float4*)src)[i];
        ushort4 o;
        o.x = f32_to_bf16(f.x); o.y = f32_to_bf16(f.y);
        o.z = f32_to_bf16(f.z); o.w = f32_to_bf16(f.w);
        ((ushort4*)dst)[i] = o;
    }
}

// ---------------- transpose + cast: src f32 [R][C] -> dst bf16 [C][R] ----------------
__global__ void transpose_cast(const float* __restrict__ src,
                               unsigned short* __restrict__ dst, int R, int C) {
    __shared__ float tile[32][33];
    int c0 = blockIdx.x * 32, r0 = blockIdx.y * 32;
    int tx = threadIdx.x, ty = threadIdx.y;   // 32 x 8
    #pragma unroll
    for (int i = 0; i < 32; i += 8)
        tile[ty + i][tx] = src[(long)(r0 + ty + i) * C + c0 + tx];
    __syncthreads();
    #pragma unroll
    for (int i = 0; i < 32; i += 8)
        dst[(long)(c0 + ty + i) * R + r0 + tx] = f32_to_bf16(tile[tx][ty + i]);
}

// ---------------- bf16 MFMA GEMM, BK=64, async staging, XOR-swizzled LDS ----------------
// LDS chunk swizzle: row r's 16-B chunk c stored at physical chunk c^(r&7).
// Staging permutes which global chunk each lane fetches (same 128-B segments,
// coalescing unchanged); fragment reads hit 8 distinct 4-bank groups per
// 8-lane phase -> conflict-free (was ~16-way at stride 128 B).
// If vT_out != nullptr, tiles with gcol >= v_col0 (the V section of QKV) are
// written TRANSPOSED into vT[b,h,d][t] instead of row-major Cout.
template<bool OUT_BF16>
__global__ __launch_bounds__(256) void gemm_bt_bias(
    const unsigned short* __restrict__ A,    // [M][K] bf16
    const unsigned short* __restrict__ Bt,   // [N][K] bf16
    const float* __restrict__ bias,          // [N] f32
    void* __restrict__ Cout,                 // [M][N] bf16 or f32
    int M, int N, int K, int scale_ncols, float scale,
    unsigned short* __restrict__ vT_out, int v_col0, int Tlog2, int Hn)
{
    __shared__ __align__(16) unsigned short As[128 * 64];
    __shared__ __align__(16) unsigned short Bs[128 * 64];

    const int tid  = threadIdx.x;
    const int m0   = blockIdx.x * 128;
    const int n0   = blockIdx.y * 128;
    const int w    = tid >> 6, lane = tid & 63;
    const int quad = lane >> 4, lr = lane & 15;
    const int wm   = (w >> 1) * 64, wn = (w & 1) * 64;

    f32x4 acc[4][4];
    #pragma unroll
    for (int i = 0; i < 4; i++)
        #pragma unroll
        for (int j = 0; j < 4; j++)
            acc[i][j] = (f32x4){0.f, 0.f, 0.f, 0.f};

    // staging: call c covers rows c*32 + w*8 + (lane>>3); lane fetches the
    // SWIZZLED global chunk ((lane&7) ^ (lane>>3)) so LDS physical chunk
    // (lane&7) of row r holds global chunk (lane&7)^(r&7).
    const int srow8 = lane >> 3;
    const int skoff = ((lane & 7) ^ srow8) * 8;

    for (int k0 = 0; k0 < K; k0 += 64) {
        __syncthreads();
        #pragma unroll
        for (int c = 0; c < 4; c++) {
            const int rbase = c * 32 + w * 8;
            async_load16(&A [(long)(m0 + rbase + srow8) * K + k0 + skoff], &As[rbase * 64]);
            async_load16(&Bt[(long)(n0 + rbase + srow8) * K + k0 + skoff], &Bs[rbase * 64]);
        }
        __syncthreads();   // barrier drain waits vmcnt(0)

        #pragma unroll
        for (int ks = 0; ks < 2; ks++) {
            bf16x8 af[4], bfr[4];
            #pragma unroll
            for (int i = 0; i < 4; i++)
                af[i] = *(const bf16x8*)&As[(wm + i * 16 + lr) * 64 +
                                            (((ks * 4 + quad) ^ (lr & 7)) << 3)];
            #pragma unroll
            for (int j = 0; j < 4; j++)
                bfr[j] = *(const bf16x8*)&Bs[(wn + j * 16 + lr) * 64 +
                                             (((ks * 4 + quad) ^ (lr & 7)) << 3)];
            #pragma unroll
            for (int i = 0; i < 4; i++)
                #pragma unroll
                for (int j = 0; j < 4; j++)
                    acc[i][j] = __builtin_amdgcn_mfma_f32_16x16x32_bf16(af[i], bfr[j], acc[i][j], 0, 0, 0);
        }
    }

    #pragma unroll
    for (int i = 0; i < 4; i++) {
        #pragma unroll
        for (int j = 0; j < 4; j++) {
            int gcol = n0 + wn + j * 16 + lr;
            float bv = bias[gcol];
            if (OUT_BF16 && vT_out != nullptr && gcol >= v_col0) {
                // V section: write transposed into vT[(b*H + h)*64 + d][t]
                int hd  = gcol - v_col0;               // h*64 + d
                int t0g = m0 + wm + i * 16 + quad * 4; // 4 consecutive t
                int bi  = t0g >> Tlog2;
                int tl  = t0g & ((1 << Tlog2) - 1);
                unsigned short pk[4];
                #pragma unroll
                for (int r = 0; r < 4; r++)
                    pk[r] = f32_to_bf16(acc[i][j][r] + bv);
                *(uint2*)&vT_out[((long)bi * Hn * 64 + hd) * (1 << Tlog2) + tl] =
                    *(const uint2*)pk;
            } else {
                float sc = (gcol < scale_ncols) ? scale : 1.0f;
                #pragma unroll
                for (int r = 0; r < 4; r++) {
                    int grow = m0 + wm + i * 16 + quad * 4 + r;
                    float v = (acc[i][j][r] + bv) * sc;
                    if (OUT_BF16)
                        ((unsigned short*)Cout)[(long)grow * N + gcol] = f32_to_bf16(v);
                    else
                        ((float*)Cout)[(long)grow * N + gcol] = v;
                }
            }
        }
    }
}

// ---------------- V transpose (fallback if workspace too small) ----------------
__global__ __launch_bounds__(256) void transpose_v(
    const unsigned short* __restrict__ qkv,  // [B*T][3C] bf16
    unsigned short* __restrict__ vT,         // [B*H*64][T] bf16
    int T, int C3, int C, int H)
{
    __shared__ __align__(16) unsigned short tile[64 * 72];  // [t][d]
    const int tid = threadIdx.x;
    const int t0 = blockIdx.x * 64, h = blockIdx.y, b = blockIdx.z;
    const long ibase = ((long)b * T + t0) * C3 + 2 * C + h * 64;
    #pragma unroll
    for (int c = tid; c < 512; c += 256) {
        int r = c >> 3, off = (c & 7) * 8;
        *(uint4*)&tile[r * 72 + off] = *(const uint4*)&qkv[ibase + (long)r * C3 + off];
    }
    __syncthreads();
    const long obase = (long)((b * H + h) * 64) * T + t0;
    #pragma unroll
    for (int c = tid; c < 512; c += 256) {
        int d = c & 63, tc = c >> 6;
        unsigned short tmp[8];
        #pragma unroll
        for (int j = 0; j < 8; j++)
            tmp[j] = tile[(tc * 8 + j) * 72 + d];
        *(uint4*)&vT[obase + (long)d * T + tc * 8] = *(const uint4*)tmp;
    }
}

// ---------------- MFMA causal flash attention ----------------
// Q-tile 128, Q in registers, transposed-S (P written [q][key] as b64),
// fixed-reference softmax (m=0, scale folded into q), raw v_exp_f32.
// LDS = Ks+Vs+Ps = 36.9 KB; launch_bounds(256,3).
__global__ __launch_bounds__(256, 3) void attn_mfma(
    const unsigned short* __restrict__ qkv,  // [B*T][3C] bf16 (q pre-scaled)
    const unsigned short* __restrict__ vT,   // [B*H*64][T] bf16
    unsigned short* __restrict__ yb,         // [B*T][C]  bf16
    int T, int C3, int C, int H, int NT)
{
    constexpr int SQ = 72;
    __shared__ __align__(16) unsigned short Ks[64 * SQ];
    __shared__ __align__(16) unsigned short Vs[64 * SQ];    // [d][key]
    __shared__ __align__(16) unsigned short Ps[128 * SQ];   // [q][key]

    const int tid = threadIdx.x;
    const int h   = blockIdx.y;
    const int b   = blockIdx.z;
    const long rowbase = (long)b * T;
    const long vtbase  = (long)((b * H + h) * 64) * T;

    const int w = tid >> 6, lane = tid & 63;
    const int quad = lane >> 4, lr = lane & 15;

    const int r0 = tid >> 3, off0 = (tid & 7) * 8;   // staging: rows 0..31, 16B chunks
    const int r1 = r0 + 32;

    for (int t = 0; t < 2; t++) {
        const int qt = (t == 0) ? blockIdx.x : (NT - 1 - blockIdx.x);
        const int q0 = qt * 128;
        const int nb = 2 * qt + 2;

        const int wrow0 = w * 32;            // wave's first row within tile
        const int wrowmax = q0 + wrow0 + 31; // wave's last global row

        // Q fragments in registers: [st][ks]
        bf16x8 aq[2][2];
        #pragma unroll
        for (int st = 0; st < 2; st++)
            #pragma unroll
            for (int ks = 0; ks < 2; ks++)
                aq[st][ks] = *(const bf16x8*)&qkv[
                    (rowbase + q0 + wrow0 + st * 16 + lr) * (long)C3 + h * 64 + ks * 32 + quad * 8];

        // prefetch kb=0 K/V into registers
        uint4 pk0, pk1, pv0, pv1;
        {
            long g0 = (rowbase + r0) * (long)C3 + C + h * 64 + off0;
            long g1 = (rowbase + r1) * (long)C3 + C + h * 64 + off0;
            pk0 = *(const uint4*)&qkv[g0];
            pk1 = *(const uint4*)&qkv[g1];
            pv0 = *(const uint4*)&vT[vtbase + (long)r0 * T + off0];
            pv1 = *(const uint4*)&vT[vtbase + (long)r1 * T + off0];
        }

        f32x4 oA[2][4];
        float lp[2] = {0.f, 0.f};
        #pragma unroll
        for (int st = 0; st < 2; st++)
            #pragma unroll
            for (int j = 0; j < 4; j++) oA[st][j] = (f32x4){0.f, 0.f, 0.f, 0.f};

        for (int kb = 0; kb < nb; kb++) {
            __syncthreads();   // prior-iteration Ks/Vs reads done
            *(uint4*)&Ks[r0 * SQ + off0] = pk0;
            *(uint4*)&Ks[r1 * SQ + off0] = pk1;
            *(uint4*)&Vs[r0 * SQ + off0] = pv0;
            *(uint4*)&Vs[r1 * SQ + off0] = pv1;
            __syncthreads();

            // prefetch kb+1 (latency overlaps compute below)
            if (kb + 1 < nb) {
                long g0 = (rowbase + (kb + 1) * 64 + r0) * (long)C3 + C + h * 64 + off0;
                long g1 = (rowbase + (kb + 1) * 64 + r1) * (long)C3 + C + h * 64 + off0;
                pk0 = *(const uint4*)&qkv[g0];
                pk1 = *(const uint4*)&qkv[g1];
                pv0 = *(const uint4*)&vT[vtbase + (long)r0 * T + (kb + 1) * 64 + off0];
                pv1 = *(const uint4*)&vT[vtbase + (long)r1 * T + (kb + 1) * 64 + off0];
            }

            // wave-uniform skip: all 32 rows fully masked
            if (kb * 64 > wrowmax) continue;   // no barriers inside guarded region

            // ---- S^T = K Q^T : D[m=key][n=q] per 16x16 tile ----
            f32x4 sT[2][4];
            #pragma unroll
            for (int st = 0; st < 2; st++)
                #pragma unroll
                for (int j = 0; j < 4; j++) sT[st][j] = (f32x4){0.f, 0.f, 0.f, 0.f};
            #pragma unroll
            for (int ks = 0; ks < 2; ks++) {
                #pragma unroll
                for (int jt = 0; jt < 4; jt++) {
                    bf16x8 kf = *(const bf16x8*)&Ks[(jt * 16 + lr) * SQ + ks * 32 + quad * 8];
                    sT[0][jt] = __builtin_amdgcn_mfma_f32_16x16x32_bf16(kf, aq[0][ks], sT[0][jt], 0, 0, 0);
                    sT[1][jt] = __builtin_amdgcn_mfma_f32_16x16x32_bf16(kf, aq[1][ks], sT[1][jt], 0, 0, 0);
                }
            }

            // ---- softmax (fixed ref m=0): lane owns q = st*16+lr, keys jt*16+quad*4+r ----
            const bool diag = (kb * 64 + 63 > q0 + wrow0);   // any key > wave's smallest q
            #pragma unroll
            for (int st = 0; st < 2; st++) {
                const int qg = q0 + wrow0 + st * 16 + lr;
                float rowsum = 0.f;
                #pragma unroll
                for (int jt = 0; jt < 4; jt++) {
                    float p[4];
                    #pragma unroll
                    for (int r = 0; r < 4; r++) {
                        float sv = sT[st][jt][r];
                        if (diag && (kb * 64 + jt * 16 + quad * 4 + r) > qg) sv = -1e30f;
                        p[r] = __builtin_amdgcn_exp2f(sv);
                        rowsum += p[r];
                    }
                    *(uint2*)&Ps[(wrow0 + st * 16 + lr) * SQ + jt * 16 + quad * 4] =
                        make_uint2(pack_bf16x2(p[0], p[1]), pack_bf16x2(p[2], p[3]));
                }
                lp[st] += rowsum;
            }
            // same-wave Ps write->read: program order + compiler lgkmcnt

            // ---- O += P V ----
            #pragma unroll
            for (int ks = 0; ks < 2; ks++) {
                bf16x8 ap0 = *(const bf16x8*)&Ps[(wrow0 + lr) * SQ + ks * 32 + quad * 8];
                bf16x8 ap1 = *(const bf16x8*)&Ps[(wrow0 + 16 + lr) * SQ + ks * 32 + quad * 8];
                #pragma unroll
                for (int jt = 0; jt < 4; jt++) {
                    bf16x8 bv = *(const bf16x8*)&Vs[(jt * 16 + lr) * SQ + ks * 32 + quad * 8];
                    oA[0][jt] = __builtin_amdgcn_mfma_f32_16x16x32_bf16(ap0, bv, oA[0][jt], 0, 0, 0);
                    oA[1][jt] = __builtin_amdgcn_mfma_f32_16x16x32_bf16(ap1, bv, oA[1][jt], 0, 0, 0);
                }
            }
        }

        // ---- reduce row-sums across quads, redistribute, normalize + store ----
        #pragma unroll
        for (int st = 0; st < 2; st++) {
            float l = lp[st];
            l += __shfl_xor(l, 16);
            l += __shfl_xor(l, 32);
            float inv = 1.f / l;   // valid for q = st*16+lr (all quads hold it)
            #pragma unroll
            for (int r = 0; r < 4; r++) {
                float invr = __shfl(inv, quad * 4 + r, 16);  // inv for row quad*4+r
                long grow = rowbase + q0 + wrow0 + st * 16 + quad * 4 + r;
                #pragma unroll
                for (int jt = 0; jt < 4; jt++)
                    yb[grow * C + h * 64 + jt * 16 + lr] = f32_to_bf16(oA[st][jt][r] * invr);
            }
        }
    }
}

extern "C" void kernel_launch(void* const* d_in, const int* in_sizes, int n_in,
                              void* d_out, int out_size, void* d_ws, size_t ws_size,
                              hipStream_t stream) {
    const float* x      = (const float*)d_in[0];
    const float* W_attn = (const float*)d_in[1];
    const float* b_attn = (const float*)d_in[2];
    const float* W_proj = (const float*)d_in[3];
    const float* b_proj = (const float*)d_in[4];
    float* out = (float*)d_out;

    const int B = 4, T = 2048, C = 1024, H = 16;
    const int M  = B * T;     // 8192
    const int C3 = 3 * C;     // 3072
    const int NT = T / 128;   // 16
    const int Tlog2 = 11;     // T = 2048
    // log2(e)/sqrt(64): folds softmax base-2 conversion and 1/sqrt(hd) into q
    const float scale2 = 0.18033688011112042f;

    char* ws = (char*)d_ws;
    size_t off = 0;
    auto carve = [&](size_t bytes) {
        char* p = ws + off;
        off += (bytes + 255) & ~(size_t)255;
        return p;
    };
    unsigned short* xb   = (unsigned short*)carve((size_t)M * C * 2);    // x bf16
    unsigned short* wat  = (unsigned short*)carve((size_t)C3 * C * 2);
    unsigned short* wpt  = (unsigned short*)carve((size_t)C * C * 2);
    unsigned short* qkvb = (unsigned short*)carve((size_t)M * C3 * 2);
    unsigned short* ybuf = (unsigned short*)carve((size_t)M * C * 2);

    // vT [B*H*64][T] = 16 MB. Prefer its own buffer (enables fused V-transpose
    // in the QKV GEMM, whose A input is xb — must not alias). Fallback: alias
    // xb (dead after QKV GEMM) + separate transpose_v pass.
    const size_t vT_bytes = (size_t)B * H * 64 * T * 2;
    bool fuse_v = (off + vT_bytes) <= ws_size;
    unsigned short* vTb = fuse_v ? (unsigned short*)carve(vT_bytes) : xb;

    cast_f32_bf16<<<(M * C / 4 + 255) / 256, 256, 0, stream>>>(x, xb, M * C / 4);
    transpose_cast<<<dim3(C3 / 32, C / 32), dim3(32, 8), 0, stream>>>(W_attn, wat, C, C3);
    transpose_cast<<<dim3(C / 32, C / 32), dim3(32, 8), 0, stream>>>(W_proj, wpt, C, C);

    gemm_bt_bias<true><<<dim3(M / 128, C3 / 128), 256, 0, stream>>>(
        xb, wat, b_attn, qkvb, M, C3, C, C, scale2,
        fuse_v ? vTb : nullptr, 2 * C, Tlog2, H);

    if (!fuse_v)
        transpose_v<<<dim3(T / 64, H, B), 256, 0, stream>>>(qkvb, vTb, T, C3, C, H);

    attn_mfma<<<dim3(NT / 2, H, B), 256, 0, stream>>>(qkvb, vTb, ybuf, T, C3, C, H, NT);

    gemm_bt_bias<false><<<dim3(M / 128, C / 128), 256, 0, stream>>>(
        ybuf, wpt, b_proj, out, M, C, C, 0, 1.0f, nullptr, 1 << 30, Tlog2, H);
}